// Round 1
// baseline (239.470 us; speedup 1.0000x reference)
//
#include <hip/hip_runtime.h>
#include <math.h>

#define NLAT 128
#define NLON 256
#define LMAX 50
#define MMAX 50
#define MGRID (NLAT*NLON)   // 32768
#define BATCH 2
#define NPTS 2048
#define PI_F 3.14159265358979323846f
#define PI_D 3.14159265358979323846

// ---------------- kernel 1: cartesian -> spherical + rho ----------------
__global__ void k_sph(const float* __restrict__ target,
                      float* __restrict__ sph, float* __restrict__ rho) {
    int idx = blockIdx.x * blockDim.x + threadIdx.x;
    if (idx >= BATCH * NPTS) return;
    float x = target[idx*3+0], y = target[idx*3+1], z = target[idx*3+2];
    float r = sqrtf(x*x + y*y + z*z);
    float phi = atan2f(y, x);
    float c = z / r;
    c = fminf(1.0f, fmaxf(-1.0f, c));
    float th = acosf(c) - PI_F;
    sph[idx*2+0] = phi;
    sph[idx*2+1] = th;
    rho[idx] = r;
}

// ---------------- kernel 2: Legendre * CC-weights table (fp64, tiny) ----
// W layout: [m][l][k]  (mmax, lmax, nlat)
__global__ void k_legw(float* __restrict__ W) {
    int t = blockIdx.x * blockDim.x + threadIdx.x;
    if (t >= MMAX * NLAT) return;
    int m = t / NLAT;
    int k = t % NLAT;
    double theta = (PI_D * (double)k) / 127.0;
    double x = cos(theta), s = sin(theta);
    // Clenshaw-Curtis weight (N=127 odd -> b==2 for all k)
    double S = 0.0;
    for (int kk = 1; kk <= 63; ++kk)
        S += 2.0 / (4.0*kk*kk - 1.0) * cos(2.0 * theta * (double)kk);
    double w = (2.0/127.0) * (1.0 - S);
    if (k == 0 || k == NLAT-1) w *= 0.5;
    // pmm = P[m][m](cos theta), orthonormal, Condon-Shortley
    double pmm = sqrt(1.0 / (4.0 * PI_D));
    for (int i = 1; i <= m; ++i)
        pmm = -sqrt((2.0*i + 1.0) / (2.0*i)) * s * pmm;
    // l < m entries are zero
    for (int l = 0; l < m; ++l)
        W[(m*LMAX + l)*NLAT + k] = 0.0f;
    double Plm2 = pmm;
    W[(m*LMAX + m)*NLAT + k] = (float)(Plm2 * w);
    if (m + 1 < LMAX) {
        double Plm1 = sqrt(2.0*m + 3.0) * x * pmm;
        W[(m*LMAX + (m+1))*NLAT + k] = (float)(Plm1 * w);
        for (int l = m + 2; l < LMAX; ++l) {
            double a  = sqrt((4.0*(double)l*l - 1.0) / ((double)l*l - (double)m*m));
            double bb = sqrt(((l-1.0)*(l-1.0) - (double)m*m) /
                             (4.0*(l-1.0)*(l-1.0) - 1.0));
            double P = a * (x * Plm1 - bb * Plm2);
            W[(m*LMAX + l)*NLAT + k] = (float)(P * w);
            Plm2 = Plm1; Plm1 = P;
        }
    }
}

// ---------------- kernel 3: 3-NN + distance-weighted combine -> f -------
__global__ __launch_bounds__(256)
void k_nn(const float* __restrict__ sph, const float* __restrict__ rho,
          float* __restrict__ f) {
    __shared__ float s_phi[NPTS];
    __shared__ float s_th[NPTS];
    __shared__ float s_rho[NPTS];
    int b = blockIdx.y;
    const float* sb = sph + b * NPTS * 2;
    const float* rb = rho + b * NPTS;
    for (int i = threadIdx.x; i < NPTS; i += blockDim.x) {
        s_phi[i] = sb[i*2+0];
        s_th[i]  = sb[i*2+1];
        s_rho[i] = rb[i];
    }
    __syncthreads();
    int gp = blockIdx.x * blockDim.x + threadIdx.x;   // 0..32767
    int gi = gp >> 8;        // lat index
    int gj = gp & 255;       // lon index
    float gx = (float)gi * (PI_F / 128.0f);
    float gy = (float)(gj - 128) * (PI_F / 128.0f);
    float d0 = 1e30f, d1 = 1e30f, d2 = 1e30f;
    int i0 = 0, i1 = 0, i2 = 0;
    #pragma unroll 8
    for (int n = 0; n < NPTS; ++n) {
        float dp = gx - s_phi[n];
        float dt = gy - s_th[n];
        float d = dp*dp + dt*dt;
        if (d < d2) {
            if (d < d1) {
                if (d < d0) { d2 = d1; i2 = i1; d1 = d0; i1 = i0; d0 = d; i0 = n; }
                else        { d2 = d1; i2 = i1; d1 = d;  i1 = n; }
            } else          { d2 = d;  i2 = n; }
        }
    }
    float r0 = sqrtf(d0), r1 = sqrtf(d1), r2 = sqrtf(d2);
    float sum = r0 + r1 + r2;
    float interp = (s_rho[i0]*r0 + s_rho[i1]*r1 + s_rho[i2]*r2) / sum;
    f[b * MGRID + gp] = interp;
}

// ---------------- kernel 4a: truncated real-DFT over longitude ----------
// Fre[b][k][m] = (2pi/256) * sum_j f[b][k][j] * cos(2pi*(m*j mod 256)/256)
__global__ void k_fft(const float* __restrict__ f, float* __restrict__ Fre) {
    __shared__ float row[NLON];
    __shared__ float ct[NLON];
    int bk = blockIdx.x;              // b*NLAT + k
    const float* fr = f + bk * NLON;
    for (int j = threadIdx.x; j < NLON; j += blockDim.x) {
        row[j] = fr[j];
        ct[j]  = cosf((float)j * (2.0f * PI_F / 256.0f));
    }
    __syncthreads();
    int m = threadIdx.x;
    if (m >= MMAX) return;
    float acc = 0.0f;
    #pragma unroll 8
    for (int j = 0; j < NLON; ++j) {
        int a = (m * j) & 255;
        acc += row[j] * ct[a];
    }
    Fre[bk * MMAX + m] = acc * (2.0f * PI_F / 256.0f);
}

// ---------------- kernel 4b: Legendre contraction over latitude ---------
// out[b][l][m] = sum_k W[m][l][k] * Fre[b][k][m]
__global__ void k_sht(const float* __restrict__ Fre, const float* __restrict__ W,
                      float* __restrict__ out) {
    int t = blockIdx.x * blockDim.x + threadIdx.x;
    if (t >= BATCH * LMAX * MMAX) return;
    int b = t / (LMAX * MMAX);
    int lm = t % (LMAX * MMAX);
    int l = lm / MMAX, m = lm % MMAX;
    const float* Wml = W + (m*LMAX + l) * NLAT;
    const float* Fb  = Fre + b * NLAT * MMAX + m;
    float acc = 0.0f;
    #pragma unroll 4
    for (int k = 0; k < NLAT; ++k)
        acc += Wml[k] * Fb[k * MMAX];
    out[t] = acc;
}

extern "C" void kernel_launch(void* const* d_in, const int* in_sizes, int n_in,
                              void* d_out, int out_size, void* d_ws, size_t ws_size,
                              hipStream_t stream) {
    const float* target = (const float*)d_in[0];
    float* out = (float*)d_out;

    float* ws  = (float*)d_ws;
    float* sph = ws;                          // B*NPTS*2   = 8192
    float* rho = sph + BATCH*NPTS*2;          // B*NPTS     = 4096
    float* W   = rho + BATCH*NPTS;            // 50*50*128  = 320000
    float* f   = W + MMAX*LMAX*NLAT;          // B*MGRID    = 65536
    float* Fre = f + BATCH*MGRID;             // B*128*50   = 12800

    k_sph<<<(BATCH*NPTS + 255)/256, 256, 0, stream>>>(target, sph, rho);
    k_legw<<<(MMAX*NLAT + 255)/256, 256, 0, stream>>>(W);
    dim3 nn_grid(MGRID/256, BATCH);
    k_nn<<<nn_grid, 256, 0, stream>>>(sph, rho, f);
    k_fft<<<BATCH*NLAT, 64, 0, stream>>>(f, Fre);
    k_sht<<<(BATCH*LMAX*MMAX + 255)/256, 256, 0, stream>>>(Fre, W, out);
}

// Round 2
// 140.937 us; speedup vs baseline: 1.6991x; 1.6991x over previous
//
#include <hip/hip_runtime.h>
#include <math.h>
#include <stdint.h>

#define NLAT 128
#define NLON 256
#define LMAX 50
#define MMAX 50
#define MGRID (NLAT*NLON)   // 32768
#define BATCH 2
#define NPTS 2048
#define PI_F 3.14159265358979323846f

__device__ __forceinline__ uint32_t umin32(uint32_t a, uint32_t b) { return a < b ? a : b; }
__device__ __forceinline__ uint32_t umax32(uint32_t a, uint32_t b) { return a > b ? a : b; }

// ---------------- kernel 1: cartesian -> spherical + rho ----------------
__global__ void k_sph(const float* __restrict__ target,
                      float* __restrict__ sph, float* __restrict__ rho) {
    int idx = blockIdx.x * blockDim.x + threadIdx.x;
    if (idx >= BATCH * NPTS) return;
    float x = target[idx*3+0], y = target[idx*3+1], z = target[idx*3+2];
    float r = sqrtf(x*x + y*y + z*z);
    float phi = atan2f(y, x);
    float c = z / r;
    c = fminf(1.0f, fmaxf(-1.0f, c));
    float th = acosf(c) - PI_F;
    sph[idx*2+0] = phi;
    sph[idx*2+1] = th;
    rho[idx] = r;
}

// ---------------- kernel 2: Legendre * CC-weights table (fp32) ----------
// W layout: [l][k][m]  -> W[(l*NLAT+k)*MMAX+m]  (m fastest for coalescing)
__global__ void k_legw(float* __restrict__ W) {
    int t = blockIdx.x * blockDim.x + threadIdx.x;
    if (t >= MMAX * NLAT) return;
    int m = t / NLAT;
    int k = t % NLAT;
    float theta = (PI_F * (float)k) / 127.0f;
    float x = __cosf(theta), s = __sinf(theta);
    // Clenshaw-Curtis weight (N=127 odd -> b==2 for all kk)
    float S = 0.0f;
    for (int kk = 1; kk <= 63; ++kk)
        S += 2.0f / (4.0f*kk*kk - 1.0f) * __cosf(2.0f * theta * (float)kk);
    float w = (2.0f/127.0f) * (1.0f - S);
    if (k == 0 || k == NLAT-1) w *= 0.5f;
    // pmm = P[m][m](cos theta), orthonormal, Condon-Shortley
    float pmm = sqrtf(1.0f / (4.0f * PI_F));
    for (int i = 1; i <= m; ++i)
        pmm = -sqrtf((2.0f*i + 1.0f) / (2.0f*i)) * s * pmm;
    // l < m entries are zero (must write: ws is re-poisoned each call)
    for (int l = 0; l < m; ++l)
        W[(l*NLAT + k)*MMAX + m] = 0.0f;
    float Plm2 = pmm;
    W[(m*NLAT + k)*MMAX + m] = Plm2 * w;
    if (m + 1 < LMAX) {
        float Plm1 = sqrtf(2.0f*m + 3.0f) * x * pmm;
        W[((m+1)*NLAT + k)*MMAX + m] = Plm1 * w;
        for (int l = m + 2; l < LMAX; ++l) {
            float fl = (float)l, fm2 = (float)(m*m);
            float a  = sqrtf((4.0f*fl*fl - 1.0f) / (fl*fl - fm2));
            float bb = sqrtf(((fl-1.0f)*(fl-1.0f) - fm2) /
                             (4.0f*(fl-1.0f)*(fl-1.0f) - 1.0f));
            float P = a * (x * Plm1 - bb * Plm2);
            W[(l*NLAT + k)*MMAX + m] = P * w;
            Plm2 = Plm1; Plm1 = P;
        }
    }
}

// ---------------- kernel 3: 3-NN + distance-weighted combine -> f -------
// Branchless: pack (quantized d | candidate idx) into one u32 key; positive
// fp32 bit pattern preserves ordering; low 11 mantissa bits carry the index.
__global__ __launch_bounds__(256)
void k_nn(const float* __restrict__ sph, const float* __restrict__ rho,
          float* __restrict__ f) {
    __shared__ float2 s_pt[NPTS];
    __shared__ float  s_rho[NPTS];
    int b = blockIdx.y;
    const float2* sb = (const float2*)(sph + b * NPTS * 2);
    const float*  rb = rho + b * NPTS;
    for (int i = threadIdx.x; i < NPTS; i += 256) {
        s_pt[i]  = sb[i];
        s_rho[i] = rb[i];
    }
    __syncthreads();
    int gp = blockIdx.x * 256 + threadIdx.x;   // 0..32767
    float gx = (float)(gp >> 8) * (PI_F / 128.0f);
    float gy = (float)((gp & 255) - 128) * (PI_F / 128.0f);
    uint32_t k0 = 0xFFFFFFFFu, k1 = 0xFFFFFFFFu, k2 = 0xFFFFFFFFu;
    #pragma unroll 8
    for (int n = 0; n < NPTS; ++n) {
        float2 p = s_pt[n];                       // wave-uniform broadcast
        float dp = gx - p.x;
        float dt = gy - p.y;
        float d  = fmaf(dt, dt, dp * dp);
        uint32_t key = (__float_as_uint(d) & 0xFFFFF800u) | (uint32_t)n;
        uint32_t M0 = umax32(key, k0); k0 = umin32(key, k0);
        uint32_t M1 = umax32(M0,  k1); k1 = umin32(M0,  k1);
        k2 = umin32(M1, k2);
    }
    int i0 = k0 & 2047, i1 = k1 & 2047, i2 = k2 & 2047;
    float2 p0 = s_pt[i0], p1 = s_pt[i1], p2 = s_pt[i2];
    float e;
    float r0, r1, r2;
    e = gx - p0.x; r0 = e*e; e = gy - p0.y; r0 = sqrtf(fmaf(e, e, r0));
    e = gx - p1.x; r1 = e*e; e = gy - p1.y; r1 = sqrtf(fmaf(e, e, r1));
    e = gx - p2.x; r2 = e*e; e = gy - p2.y; r2 = sqrtf(fmaf(e, e, r2));
    float sum = r0 + r1 + r2;
    float interp = (s_rho[i0]*r0 + s_rho[i1]*r1 + s_rho[i2]*r2) / sum;
    f[b * MGRID + gp] = interp;
}

// ---------------- kernel 4a: truncated real-DFT over longitude ----------
// Fre[b][k][m] = (2pi/256) * sum_j f[b][k][j] * cos(2pi*((m*j) mod 256)/256)
// 4 rows per block (one per wave), m = lane.
__global__ __launch_bounds__(256)
void k_fft(const float* __restrict__ f, float* __restrict__ Fre) {
    __shared__ float rows[4][NLON];
    int r0 = blockIdx.x * 4;                 // 64 blocks -> 256 rows
    for (int i = threadIdx.x; i < 4 * NLON; i += 256)
        rows[i >> 8][i & 255] = f[r0 * NLON + i];
    __syncthreads();
    int w = threadIdx.x >> 6;                // wave -> row
    int m = threadIdx.x & 63;
    if (m < MMAX) {
        const float* row = rows[w];
        float acc = 0.0f;
        int a = 0;                           // (m*j) mod 256, incremental
        #pragma unroll 8
        for (int j = 0; j < NLON; ++j) {
            acc = fmaf(row[j], __cosf((float)a * (2.0f * PI_F / 256.0f)), acc);
            a = (a + m) & 255;
        }
        Fre[(r0 + w) * MMAX + m] = acc * (2.0f * PI_F / 256.0f);
    }
}

// ---------------- kernel 4b: Legendre contraction over latitude ---------
// out[b][l][m] = sum_k W[l][k][m] * Fre[b][k][m]; one block per (b,l), m=lane
__global__ void k_sht(const float* __restrict__ Fre, const float* __restrict__ W,
                      float* __restrict__ out) {
    int bl = blockIdx.x;                     // 0..BATCH*LMAX-1
    int b = bl / LMAX, l = bl % LMAX;
    int m = threadIdx.x;
    if (m >= MMAX) return;
    const float* Wl = W + l * NLAT * MMAX + m;
    const float* Fb = Fre + b * NLAT * MMAX + m;
    float acc = 0.0f;
    #pragma unroll 8
    for (int k = 0; k < NLAT; ++k)
        acc = fmaf(Wl[k * MMAX], Fb[k * MMAX], acc);
    out[bl * MMAX + m] = acc;
}

extern "C" void kernel_launch(void* const* d_in, const int* in_sizes, int n_in,
                              void* d_out, int out_size, void* d_ws, size_t ws_size,
                              hipStream_t stream) {
    const float* target = (const float*)d_in[0];
    float* out = (float*)d_out;

    float* ws  = (float*)d_ws;
    float* sph = ws;                          // B*NPTS*2   = 8192
    float* rho = sph + BATCH*NPTS*2;          // B*NPTS     = 4096
    float* W   = rho + BATCH*NPTS;            // 50*128*50  = 320000
    float* f   = W + LMAX*NLAT*MMAX;          // B*MGRID    = 65536
    float* Fre = f + BATCH*MGRID;             // B*128*50   = 12800

    k_sph<<<(BATCH*NPTS + 255)/256, 256, 0, stream>>>(target, sph, rho);
    k_legw<<<(MMAX*NLAT + 255)/256, 256, 0, stream>>>(W);
    dim3 nn_grid(MGRID/256, BATCH);
    k_nn<<<nn_grid, 256, 0, stream>>>(sph, rho, f);
    k_fft<<<BATCH*NLAT/4, 256, 0, stream>>>(f, Fre);
    k_sht<<<BATCH*LMAX, 64, 0, stream>>>(Fre, W, out);
}

// Round 3
// 104.629 us; speedup vs baseline: 2.2888x; 1.3470x over previous
//
#include <hip/hip_runtime.h>
#include <math.h>
#include <stdint.h>

#define NLAT 128
#define NLON 256
#define LMAX 50
#define MMAX 50
#define MGRID (NLAT*NLON)   // 32768
#define BATCH 2
#define NPTS 2048
#define PI_F 3.14159265358979323846f

__device__ __forceinline__ uint32_t umin32(uint32_t a, uint32_t b) { return a < b ? a : b; }
__device__ __forceinline__ uint32_t umax32(uint32_t a, uint32_t b) { return a > b ? a : b; }

// ============ kernel A: cart->spherical (blocks 0..15) + Legendre*CC W
//              (blocks 16..40).  W layout: [m][l][k] = W[(m*LMAX+l)*NLAT+k]
__global__ __launch_bounds__(256)
void k_prep(const float* __restrict__ target,
            float* __restrict__ sph, float* __restrict__ rho,
            float* __restrict__ W) {
    if (blockIdx.x < 16) {
        int idx = blockIdx.x * 256 + threadIdx.x;     // 0..4095 = BATCH*NPTS
        float x = target[idx*3+0], y = target[idx*3+1], z = target[idx*3+2];
        float r = sqrtf(x*x + y*y + z*z);
        float phi = atan2f(y, x);
        float c = fminf(1.0f, fmaxf(-1.0f, z / r));
        sph[idx*2+0] = phi;
        sph[idx*2+1] = acosf(c) - PI_F;
        rho[idx] = r;
    } else {
        int t = (blockIdx.x - 16) * 256 + threadIdx.x;
        if (t >= MMAX * NLAT) return;
        int m = t / NLAT;
        int k = t % NLAT;
        float theta = (PI_F * (float)k) / 127.0f;
        float x = __cosf(theta), s = __sinf(theta);
        float S = 0.0f;
        for (int kk = 1; kk <= 63; ++kk)
            S += 2.0f / (4.0f*kk*kk - 1.0f) * __cosf(2.0f * theta * (float)kk);
        float w = (2.0f/127.0f) * (1.0f - S);
        if (k == 0 || k == NLAT-1) w *= 0.5f;
        float pmm = sqrtf(1.0f / (4.0f * PI_F));
        for (int i = 1; i <= m; ++i)
            pmm = -sqrtf((2.0f*i + 1.0f) / (2.0f*i)) * s * pmm;
        for (int l = 0; l < m; ++l)                    // must write zeros (ws poisoned)
            W[(m*LMAX + l)*NLAT + k] = 0.0f;
        float Plm2 = pmm;
        W[(m*LMAX + m)*NLAT + k] = Plm2 * w;
        if (m + 1 < LMAX) {
            float Plm1 = sqrtf(2.0f*m + 3.0f) * x * pmm;
            W[(m*LMAX + (m+1))*NLAT + k] = Plm1 * w;
            for (int l = m + 2; l < LMAX; ++l) {
                float fl = (float)l, fm2 = (float)(m*m);
                float a  = sqrtf((4.0f*fl*fl - 1.0f) / (fl*fl - fm2));
                float bb = sqrtf(((fl-1.0f)*(fl-1.0f) - fm2) /
                                 (4.0f*(fl-1.0f)*(fl-1.0f) - 1.0f));
                float P = a * (x * Plm1 - bb * Plm2);
                W[(m*LMAX + l)*NLAT + k] = P * w;
                Plm2 = Plm1; Plm1 = P;
            }
        }
    }
}

// ============ kernel B: 3-NN + weighted combine -> f.
// Block = 4 waves; each wave = same 64 grid points, disjoint 512-candidate
// partition; LDS merge of per-wave top-3 packed keys at the end.
__global__ __launch_bounds__(256, 4)
void k_nn(const float* __restrict__ sph, const float* __restrict__ rho,
          float* __restrict__ f) {
    __shared__ float2   s_pt[NPTS];
    __shared__ float    s_rho[NPTS];
    __shared__ uint32_t s_keys[4][64][3];
    int b = blockIdx.y;
    const float2* sb = (const float2*)(sph + b * NPTS * 2);
    const float*  rb = rho + b * NPTS;
    for (int i = threadIdx.x; i < NPTS; i += 256) {
        s_pt[i]  = sb[i];
        s_rho[i] = rb[i];
    }
    __syncthreads();
    int lane = threadIdx.x & 63;
    int wv   = threadIdx.x >> 6;
    int gp   = blockIdx.x * 64 + lane;                 // 0..32767
    float gx = (float)(gp >> 8) * (PI_F / 128.0f);
    float gy = (float)((gp & 255) - 128) * (PI_F / 128.0f);
    uint32_t k0 = 0xFFFFFFFFu, k1 = 0xFFFFFFFFu, k2 = 0xFFFFFFFFu;
    int base = wv * 512;
    #pragma unroll 8
    for (int j = 0; j < 512; ++j) {
        float2 p = s_pt[base + j];                     // wave-uniform broadcast
        float dp = gx - p.x;
        float dt = gy - p.y;
        float d  = fmaf(dt, dt, dp * dp);
        uint32_t key = (__float_as_uint(d) & 0xFFFFF800u) | (uint32_t)(base + j);
        uint32_t M0 = umax32(key, k0); k0 = umin32(key, k0);
        uint32_t M1 = umax32(M0,  k1); k1 = umin32(M0,  k1);
        k2 = umin32(M1, k2);
    }
    s_keys[wv][lane][0] = k0;
    s_keys[wv][lane][1] = k1;
    s_keys[wv][lane][2] = k2;
    __syncthreads();
    if (threadIdx.x < 64) {
        uint32_t m0 = 0xFFFFFFFFu, m1 = 0xFFFFFFFFu, m2 = 0xFFFFFFFFu;
        #pragma unroll
        for (int w = 0; w < 4; ++w) {
            #pragma unroll
            for (int s = 0; s < 3; ++s) {
                uint32_t key = s_keys[w][threadIdx.x][s];
                uint32_t M0 = umax32(key, m0); m0 = umin32(key, m0);
                uint32_t M1 = umax32(M0,  m1); m1 = umin32(M0,  m1);
                m2 = umin32(M1, m2);
            }
        }
        int i0 = m0 & 2047, i1 = m1 & 2047, i2 = m2 & 2047;
        float2 p0 = s_pt[i0], p1 = s_pt[i1], p2 = s_pt[i2];
        float e, r0, r1, r2;
        e = gx - p0.x; r0 = e*e; e = gy - p0.y; r0 = sqrtf(fmaf(e, e, r0));
        e = gx - p1.x; r1 = e*e; e = gy - p1.y; r1 = sqrtf(fmaf(e, e, r1));
        e = gx - p2.x; r2 = e*e; e = gy - p2.y; r2 = sqrtf(fmaf(e, e, r2));
        float sum = r0 + r1 + r2;
        float interp = (s_rho[i0]*r0 + s_rho[i1]*r1 + s_rho[i2]*r2) / sum;
        f[b * MGRID + gp] = interp;
    }
}

// ============ kernel C: fused truncated-DFT (lon) + Legendre contraction (lat)
// One block per (b, m): Fre[k] = (2pi/256) * sum_j f[b,k,j] cos(2pi (m j mod 256)/256)
// then out[b,l,m] = sum_k W[m,l,k] * Fre[k].
__global__ __launch_bounds__(256)
void k_fftsht(const float* __restrict__ f, const float* __restrict__ W,
              float* __restrict__ out) {
    __shared__ float ct[256];
    __shared__ float red[256];
    __shared__ float sFre[NLAT];
    int b = blockIdx.x / MMAX;
    int m = blockIdx.x % MMAX;
    int tid = threadIdx.x;
    ct[tid] = __cosf((float)tid * (2.0f * PI_F / 256.0f));
    __syncthreads();
    // DFT: thread = (k, jhalf); 128 j's each; cos index incremental (m*j mod 256)
    {
        int k  = tid >> 1;
        int jh = tid & 1;
        int jbase = jh << 7;
        const float* rowp = f + b * MGRID + k * NLON + jbase;
        int a = (m * jbase) & 255;
        float acc = 0.0f;
        #pragma unroll 8
        for (int j = 0; j < 128; ++j) {
            acc = fmaf(rowp[j], ct[a], acc);
            a = (a + m) & 255;
        }
        red[tid] = acc;
    }
    __syncthreads();
    if (tid < NLAT)
        sFre[tid] = (red[2*tid] + red[2*tid+1]) * (2.0f * PI_F / 256.0f);
    __syncthreads();
    // Contraction: thread = (l, kq); 32 k's each; W[m][l][:] contiguous
    {
        float acc = 0.0f;
        if (tid < 200) {
            int l  = tid >> 2;
            int kq = tid & 3;
            const float* Wp = W + (m*LMAX + l)*NLAT + kq*32;
            const float* Fp = sFre + kq*32;
            #pragma unroll 8
            for (int i = 0; i < 32; ++i)
                acc = fmaf(Wp[i], Fp[i], acc);
        }
        red[tid] = acc;
    }
    __syncthreads();
    if (tid < LMAX)
        out[(b*LMAX + tid)*MMAX + m] =
            red[4*tid] + red[4*tid+1] + red[4*tid+2] + red[4*tid+3];
}

extern "C" void kernel_launch(void* const* d_in, const int* in_sizes, int n_in,
                              void* d_out, int out_size, void* d_ws, size_t ws_size,
                              hipStream_t stream) {
    const float* target = (const float*)d_in[0];
    float* out = (float*)d_out;

    float* ws  = (float*)d_ws;
    float* sph = ws;                          // B*NPTS*2   = 8192
    float* rho = sph + BATCH*NPTS*2;          // B*NPTS     = 4096
    float* W   = rho + BATCH*NPTS;            // 50*50*128  = 320000
    float* f   = W + MMAX*LMAX*NLAT;          // B*MGRID    = 65536

    k_prep<<<16 + (MMAX*NLAT + 255)/256, 256, 0, stream>>>(target, sph, rho, W);
    dim3 nn_grid(MGRID/64, BATCH);            // 512 x 2 = 1024 blocks
    k_nn<<<nn_grid, 256, 0, stream>>>(sph, rho, f);
    k_fftsht<<<BATCH*MMAX, 256, 0, stream>>>(f, W, out);
}